// Round 8
// baseline (270.059 us; speedup 1.0000x reference)
//
#include <hip/hip_runtime.h>

#define HID 32
#define MIN_WEIGHT -100000.0f

// ---------------------------------------------------------------------------
// async global->LDS, 16B per lane, wave-uniform LDS base (+lane*16 implicit)
__device__ __forceinline__ void gld16(const float* g, float* l) {
    __builtin_amdgcn_global_load_lds(
        (const __attribute__((address_space(1))) unsigned int*)g,
        (__attribute__((address_space(3))) unsigned int*)l, 16, 0, 0);
}

// ---------------------------------------------------------------------------
// Node-stage kernel. Block = ONE wave (64 threads), TILE=16 nodes.
// Staging: 16 rows via global_load_lds (width 16), LDS linear, global source
//   chunk pre-swizzled by jc^(r&7); reads apply the same XOR -> conflict-free
//   (both-sides-or-neither). One vmcnt(0), no barriers (all wave-private).
// Compute: lane = (ng, cg) = (lane>>3, lane&7): nt=2 nodes x ct=4 cols.
//   Per 4-j: 2 ds_read_b128 (rows) + 4 L1-hot dwordx4 (W) -> 32 FMAs.
// Exchange: g -> gl[16][36] (144B stride: b128-aligned, ~2-way banks).
// Proj: pj[p][t] += g[r][j] * P[j][4cg+t], same tiling.
template <int ROW, bool TWO>
__global__ __launch_bounds__(64) void nodek(
    const float* __restrict__ emb, const int* __restrict__ n_map,
    const int* __restrict__ sel, const float* __restrict__ W,
    const float* __restrict__ P0, const float* __restrict__ P1,
    float* __restrict__ o0, float* __restrict__ o1, int n) {
    constexpr int TILE = 16;
    constexpr int CPR = ROW / 4;    // 16B chunks per row
    constexpr int RPI = 64 / CPR;   // rows per staging instruction
    constexpr int NI = TILE / RPI;  // staging instructions

    __shared__ float rows[TILE * ROW];
    __shared__ float gl[TILE * 36];

    const int lane = threadIdx.x & 63;
    const int base = blockIdx.x * TILE;

    // ---- stage 16 rows, source-swizzled ------------------------------------
    {
        const int sub = (RPI == 1) ? 0 : (lane >> (6 - (RPI == 2 ? 1 : 2)));
        const int jc = lane & (CPR - 1);
#pragma unroll
        for (int i = 0; i < NI; ++i) {
            const int r = i * RPI + sub;
            int node = base + r;
            int cn = node < n ? node : n - 1;  // clamp, keep lanes active
            int local = sel ? sel[cn] : cn;
            int gn = n_map[local];
            const float* src = emb + (size_t)gn * ROW + ((jc ^ (r & 7)) << 2);
            gld16(src, &rows[i * RPI * ROW]);  // wave-uniform LDS base
        }
    }
    asm volatile("s_waitcnt vmcnt(0)" ::: "memory");
    __builtin_amdgcn_sched_barrier(0);

    const int ng = lane >> 3;  // node pair: rows 2ng, 2ng+1
    const int cg = lane & 7;   // cols 4cg .. 4cg+3

    // ---- layer 1 -----------------------------------------------------------
    float acc[2][4] = {{0.f, 0.f, 0.f, 0.f}, {0.f, 0.f, 0.f, 0.f}};
#pragma unroll 4
    for (int j0 = 0; j0 < ROW; j0 += 4) {
        const int jc = j0 >> 2;
        float4 rr[2];
#pragma unroll
        for (int p = 0; p < 2; ++p) {
            const int r = 2 * ng + p;
            rr[p] = *(const float4*)&rows[r * ROW + ((jc ^ (r & 7)) << 2)];
        }
#pragma unroll
        for (int jj = 0; jj < 4; ++jj) {
            float4 w4 = *(const float4*)&W[(size_t)(j0 + jj) * HID + 4 * cg];
#pragma unroll
            for (int p = 0; p < 2; ++p) {
                float rv = ((const float*)&rr[p])[jj];
                acc[p][0] = fmaf(rv, w4.x, acc[p][0]);
                acc[p][1] = fmaf(rv, w4.y, acc[p][1]);
                acc[p][2] = fmaf(rv, w4.z, acc[p][2]);
                acc[p][3] = fmaf(rv, w4.w, acc[p][3]);
            }
        }
    }

    // ---- relu -> exchange --------------------------------------------------
#pragma unroll
    for (int p = 0; p < 2; ++p) {
        float4 v = {fmaxf(acc[p][0], 0.f), fmaxf(acc[p][1], 0.f),
                    fmaxf(acc[p][2], 0.f), fmaxf(acc[p][3], 0.f)};
        *(float4*)&gl[(2 * ng + p) * 36 + 4 * cg] = v;
    }

    // ---- projections -------------------------------------------------------
    float pj0[2][4] = {{0.f, 0.f, 0.f, 0.f}, {0.f, 0.f, 0.f, 0.f}};
    float pj1[2][4] = {{0.f, 0.f, 0.f, 0.f}, {0.f, 0.f, 0.f, 0.f}};
#pragma unroll
    for (int j0 = 0; j0 < HID; j0 += 4) {
        float4 g4[2];
#pragma unroll
        for (int p = 0; p < 2; ++p)
            g4[p] = *(const float4*)&gl[(2 * ng + p) * 36 + j0];
#pragma unroll
        for (int jj = 0; jj < 4; ++jj) {
            float4 wa = *(const float4*)&P0[(size_t)(j0 + jj) * HID + 4 * cg];
            float4 wb = wa;
            if (TWO) wb = *(const float4*)&P1[(size_t)(j0 + jj) * HID + 4 * cg];
#pragma unroll
            for (int p = 0; p < 2; ++p) {
                float gv = ((const float*)&g4[p])[jj];
                pj0[p][0] = fmaf(gv, wa.x, pj0[p][0]);
                pj0[p][1] = fmaf(gv, wa.y, pj0[p][1]);
                pj0[p][2] = fmaf(gv, wa.z, pj0[p][2]);
                pj0[p][3] = fmaf(gv, wa.w, pj0[p][3]);
                if (TWO) {
                    pj1[p][0] = fmaf(gv, wb.x, pj1[p][0]);
                    pj1[p][1] = fmaf(gv, wb.y, pj1[p][1]);
                    pj1[p][2] = fmaf(gv, wb.z, pj1[p][2]);
                    pj1[p][3] = fmaf(gv, wb.w, pj1[p][3]);
                }
            }
        }
    }

    // ---- stores (8 lanes x 16B = 128B contiguous per node) -----------------
#pragma unroll
    for (int p = 0; p < 2; ++p) {
        int node = base + 2 * ng + p;
        if (node < n) {
            float4 v = {pj0[p][0], pj0[p][1], pj0[p][2], pj0[p][3]};
            *(float4*)&o0[(size_t)node * HID + 4 * cg] = v;
            if (TWO) {
                float4 u = {pj1[p][0], pj1[p][1], pj1[p][2], pj1[p][3]};
                *(float4*)&o1[(size_t)node * HID + 4 * cg] = u;
            }
        }
    }
}

// ---------------------------------------------------------------------------
// Per-edge: att = relu(SA[src] + DB[dst] + t2[batch] + be1) @ We2 + be2
// Writes att to its own slab and MIN_WEIGHT to the other slab (the two hop
// index sets partition [0,E), so the two edge launches cover all of d_out).
__global__ __launch_bounds__(256) void edge_kernel(
    const int* __restrict__ hop_idx, int n_e, const int* __restrict__ src,
    const int* __restrict__ dst, const int* __restrict__ e_batch,
    const float* __restrict__ SA, const float* __restrict__ DB,
    const float* __restrict__ t2, const float* __restrict__ be1,
    const float* __restrict__ We2, const float* __restrict__ be2,
    float* __restrict__ out_att, float* __restrict__ out_min) {
    int i = blockIdx.x * blockDim.x + threadIdx.x;
    if (i >= n_e) return;
    int e = hop_idx[i];
    const float* sv = SA + (size_t)src[e] * HID;
    const float* dv = DB + (size_t)dst[e] * HID;
    const float* tv = t2 + (size_t)e_batch[e] * HID;
    float att = be2[0];
#pragma unroll
    for (int k = 0; k < HID; k += 4) {
        float4 s4 = *(const float4*)(sv + k);
        float4 d4 = *(const float4*)(dv + k);
        float4 t4 = *(const float4*)(tv + k);
        float h;
        h = fmaxf(s4.x + d4.x + t4.x + be1[k + 0], 0.f); att = fmaf(h, We2[k + 0], att);
        h = fmaxf(s4.y + d4.y + t4.y + be1[k + 1], 0.f); att = fmaf(h, We2[k + 1], att);
        h = fmaxf(s4.z + d4.z + t4.z + be1[k + 2], 0.f); att = fmaf(h, We2[k + 2], att);
        h = fmaxf(s4.w + d4.w + t4.w + be1[k + 3], 0.f); att = fmaf(h, We2[k + 3], att);
    }
    out_att[e] = att;
    out_min[e] = MIN_WEIGHT;
}

// ---------------------------------------------------------------------------
extern "C" void kernel_launch(void* const* d_in, const int* in_sizes, int n_in,
                              void* d_out, int out_size, void* d_ws, size_t ws_size,
                              hipStream_t stream) {
    const float* emb0 = (const float*)d_in[0];
    const float* emb1 = (const float*)d_in[1];
    const float* emb2 = (const float*)d_in[2];
    const int* n_map = (const int*)d_in[3];
    const int* src = (const int*)d_in[4];
    const int* dst = (const int*)d_in[5];
    const int* e_batch = (const int*)d_in[6];
    const int* offset_node = (const int*)d_in[7];
    const int* one_hop = (const int*)d_in[8];
    const int* two_hop = (const int*)d_in[9];
    const float* W0 = (const float*)d_in[10];
    const float* W1 = (const float*)d_in[11];
    const float* W2 = (const float*)d_in[12];
    const float* We1 = (const float*)d_in[13];
    const float* be1 = (const float*)d_in[14];
    const float* We2 = (const float*)d_in[15];
    const float* be2 = (const float*)d_in[16];

    const int n_nodes = in_sizes[3];
    const int E = in_sizes[4];
    const int batch = in_sizes[7];
    const int H1 = in_sizes[8];  // one-hop edge count
    const int H2 = in_sizes[9];  // two-hop edge count

    float* out = (float*)d_out;

    const float* A = We1;             // rows 0..31   (multiplies s)
    const float* B = We1 + 32 * HID;  // rows 32..63  (multiplies d)
    const float* T = We1 + 64 * HID;  // rows 64..95  (multiplies t)

    // workspace layout: a0 | a1 | b1 | b2 | t2
    float* a0 = (float*)d_ws;
    float* a1 = a0 + (size_t)n_nodes * HID;
    float* b1 = a1 + (size_t)n_nodes * HID;
    float* b2 = b1 + (size_t)n_nodes * HID;
    float* t2 = b2 + (size_t)n_nodes * HID;

    const int nblk = (n_nodes + 15) / 16;
    // a0 = relu(emb0@W0)@A
    nodek<128, false><<<nblk, 64, 0, stream>>>(
        emb0, n_map, nullptr, W0, A, nullptr, a0, nullptr, n_nodes);
    // a1 = relu(emb1@W1)@A ; b1 = relu(emb1@W1)@B
    nodek<256, true><<<nblk, 64, 0, stream>>>(
        emb1, n_map, nullptr, W1, A, B, a1, b1, n_nodes);
    // b2 = relu(emb2@W2)@B
    nodek<64, false><<<nblk, 64, 0, stream>>>(
        emb2, n_map, nullptr, W2, B, nullptr, b2, nullptr, n_nodes);
    // t2 = relu(emb2[n_map[offset_node]]@W2)@T
    nodek<64, false><<<(batch + 15) / 16, 64, 0, stream>>>(
        emb2, n_map, offset_node, W2, T, nullptr, t2, nullptr, batch);

    // one-hop edges: att -> slab 1, MIN -> slab 0 (src via W1@A, dst via W2@B)
    edge_kernel<<<(H1 + 255) / 256, 256, 0, stream>>>(
        one_hop, H1, src, dst, e_batch, a1, b2, t2, be1, We2, be2,
        out + (size_t)E, out);
    // two-hop edges: att -> slab 0, MIN -> slab 1 (src via W0@A, dst via W1@B)
    edge_kernel<<<(H2 + 255) / 256, 256, 0, stream>>>(
        two_hop, H2, src, dst, e_batch, a0, b1, t2, be1, We2, be2,
        out, out + (size_t)E);
}

// Round 9
// 251.877 us; speedup vs baseline: 1.0722x; 1.0722x over previous
//
#include <hip/hip_runtime.h>

#define HID 32
#define MIN_WEIGHT -100000.0f

// ---------------------------------------------------------------------------
// async global->LDS, 16B per lane, wave-uniform LDS base (+lane*16 implicit)
__device__ __forceinline__ void gld16(const float* g, float* l) {
    __builtin_amdgcn_global_load_lds(
        (const __attribute__((address_space(1))) unsigned int*)g,
        (__attribute__((address_space(3))) unsigned int*)l, 16, 0, 0);
}

// ---------------------------------------------------------------------------
// One 64-node tile of the node stage, processed by a 256-thread / 4-wave
// block. Wave w owns rows [w*16, w*16+16) END-TO-END (stage + compute):
// no __syncthreads anywhere.
//   staging : global_load_lds width-16, LDS linear, global source chunk
//             pre-swizzled jc^(r&7); reads use the same XOR (involution).
//   layer 1 : lane=(ng 0..7, cg 0..7): nt=2 rows x ct=4 cols; per 4-j step
//             2 ds_read_b128 (rows, 2-way banks) + 4 dwordx4 (W, L1-hot)
//             feed 32 FMAs.
//   exchange: g -> gl[r][36] wave-private (b128-aligned, <=4-way banks).
//   proj    : pj += g * P[j][4cg+t], same tiling; coalesced float4 stores.
template <int ROW, bool TWO, bool SEL>
__device__ __forceinline__ void node_tile(
    const float* __restrict__ emb, const int* __restrict__ n_map,
    const int* __restrict__ sel, const float* __restrict__ W,
    const float* __restrict__ P0, const float* __restrict__ P1,
    float* __restrict__ o0, float* __restrict__ o1, int n, int base,
    float* __restrict__ rows, float* __restrict__ gl) {
    constexpr int CPR = ROW / 4;   // 16B chunks per row
    constexpr int RPI = 64 / CPR;  // rows per staging instruction
    constexpr int NI = 16 / RPI;   // staging instructions per wave

    const int w = threadIdx.x >> 6;
    const int lane = threadIdx.x & 63;

    // ---- stage my wave's 16 rows ------------------------------------------
    {
        int sub, jc;
        if (RPI == 1) { sub = 0;         jc = lane; }
        else if (RPI == 2) { sub = lane >> 5; jc = lane & 31; }
        else { sub = lane >> 4; jc = lane & 15; }  // RPI == 4
#pragma unroll
        for (int i = 0; i < NI; ++i) {
            const int rr = w * 16 + i * RPI + sub;  // row in tile
            int node = base + rr;
            int cn = node < n ? node : n - 1;       // clamp, lanes stay active
            int local = SEL ? sel[cn] : cn;
            int gn = n_map[local];
            const float* src = emb + (size_t)gn * ROW + ((jc ^ (rr & 7)) << 2);
            gld16(src, rows + (size_t)(w * 16 + i * RPI) * ROW);
        }
    }
    asm volatile("s_waitcnt vmcnt(0)" ::: "memory");
    __builtin_amdgcn_sched_barrier(0);

    const int ng = lane >> 3;  // row pair within my 16: rows 2ng, 2ng+1
    const int cg = lane & 7;   // cols 4cg .. 4cg+3
    const int r0 = w * 16 + 2 * ng;
    const int r1 = r0 + 1;

    // ---- layer 1 -----------------------------------------------------------
    float acc[2][4] = {{0.f, 0.f, 0.f, 0.f}, {0.f, 0.f, 0.f, 0.f}};
#pragma unroll 4
    for (int j0 = 0; j0 < ROW; j0 += 4) {
        const int jc = j0 >> 2;
        float4 rA = *(const float4*)&rows[(size_t)r0 * ROW + ((jc ^ (r0 & 7)) << 2)];
        float4 rB = *(const float4*)&rows[(size_t)r1 * ROW + ((jc ^ (r1 & 7)) << 2)];
#pragma unroll
        for (int jj = 0; jj < 4; ++jj) {
            float4 w4 = *(const float4*)&W[(size_t)(j0 + jj) * HID + 4 * cg];
            float ra = ((const float*)&rA)[jj];
            float rb = ((const float*)&rB)[jj];
            acc[0][0] = fmaf(ra, w4.x, acc[0][0]);
            acc[0][1] = fmaf(ra, w4.y, acc[0][1]);
            acc[0][2] = fmaf(ra, w4.z, acc[0][2]);
            acc[0][3] = fmaf(ra, w4.w, acc[0][3]);
            acc[1][0] = fmaf(rb, w4.x, acc[1][0]);
            acc[1][1] = fmaf(rb, w4.y, acc[1][1]);
            acc[1][2] = fmaf(rb, w4.z, acc[1][2]);
            acc[1][3] = fmaf(rb, w4.w, acc[1][3]);
        }
    }

    // ---- relu -> wave-private exchange ------------------------------------
    {
        float4 v0 = {fmaxf(acc[0][0], 0.f), fmaxf(acc[0][1], 0.f),
                     fmaxf(acc[0][2], 0.f), fmaxf(acc[0][3], 0.f)};
        float4 v1 = {fmaxf(acc[1][0], 0.f), fmaxf(acc[1][1], 0.f),
                     fmaxf(acc[1][2], 0.f), fmaxf(acc[1][3], 0.f)};
        *(float4*)&gl[r0 * 36 + 4 * cg] = v0;
        *(float4*)&gl[r1 * 36 + 4 * cg] = v1;
    }

    // ---- projections -------------------------------------------------------
    float pj0[2][4] = {{0.f, 0.f, 0.f, 0.f}, {0.f, 0.f, 0.f, 0.f}};
    float pj1[2][4] = {{0.f, 0.f, 0.f, 0.f}, {0.f, 0.f, 0.f, 0.f}};
#pragma unroll
    for (int j0 = 0; j0 < HID; j0 += 4) {
        float4 gA = *(const float4*)&gl[r0 * 36 + j0];
        float4 gB = *(const float4*)&gl[r1 * 36 + j0];
#pragma unroll
        for (int jj = 0; jj < 4; ++jj) {
            float4 wa = *(const float4*)&P0[(size_t)(j0 + jj) * HID + 4 * cg];
            float ga = ((const float*)&gA)[jj];
            float gb = ((const float*)&gB)[jj];
            pj0[0][0] = fmaf(ga, wa.x, pj0[0][0]);
            pj0[0][1] = fmaf(ga, wa.y, pj0[0][1]);
            pj0[0][2] = fmaf(ga, wa.z, pj0[0][2]);
            pj0[0][3] = fmaf(ga, wa.w, pj0[0][3]);
            pj0[1][0] = fmaf(gb, wa.x, pj0[1][0]);
            pj0[1][1] = fmaf(gb, wa.y, pj0[1][1]);
            pj0[1][2] = fmaf(gb, wa.z, pj0[1][2]);
            pj0[1][3] = fmaf(gb, wa.w, pj0[1][3]);
            if (TWO) {
                float4 wb = *(const float4*)&P1[(size_t)(j0 + jj) * HID + 4 * cg];
                pj1[0][0] = fmaf(ga, wb.x, pj1[0][0]);
                pj1[0][1] = fmaf(ga, wb.y, pj1[0][1]);
                pj1[0][2] = fmaf(ga, wb.z, pj1[0][2]);
                pj1[0][3] = fmaf(ga, wb.w, pj1[0][3]);
                pj1[1][0] = fmaf(gb, wb.x, pj1[1][0]);
                pj1[1][1] = fmaf(gb, wb.y, pj1[1][1]);
                pj1[1][2] = fmaf(gb, wb.z, pj1[1][2]);
                pj1[1][3] = fmaf(gb, wb.w, pj1[1][3]);
            }
        }
    }

    // ---- stores (8 lanes x 16B = 128B contiguous per node) -----------------
#pragma unroll
    for (int p = 0; p < 2; ++p) {
        int node = base + r0 + p - (w * 16) + (w * 16);  // = base + (r0 + p)
        node = base + (p == 0 ? r0 : r1);
        if (node < n) {
            float4 v = {pj0[p][0], pj0[p][1], pj0[p][2], pj0[p][3]};
            *(float4*)&o0[(size_t)node * HID + 4 * cg] = v;
            if (TWO) {
                float4 u = {pj1[p][0], pj1[p][1], pj1[p][2], pj1[p][3]};
                *(float4*)&o1[(size_t)node * HID + 4 * cg] = u;
            }
        }
    }
}

// ---------------------------------------------------------------------------
// Fused node-stage kernel: all four jobs in one dispatch (job table by bid).
__global__ __launch_bounds__(256) void nodek_fused(
    const float* __restrict__ emb0, const float* __restrict__ emb1,
    const float* __restrict__ emb2, const int* __restrict__ n_map,
    const int* __restrict__ offset_node, const float* __restrict__ W0,
    const float* __restrict__ W1, const float* __restrict__ W2,
    const float* __restrict__ We1, float* __restrict__ a0,
    float* __restrict__ a1, float* __restrict__ b1, float* __restrict__ b2,
    float* __restrict__ t2, int n_nodes, int batch, int nt) {
    __shared__ float rows[64 * 256];  // 64 KB (max job: ROW=256)
    __shared__ float gl[64 * 36];     // 9.2 KB

    const float* A = We1;             // rows 0..31
    const float* B = We1 + 32 * HID;  // rows 32..63
    const float* T = We1 + 64 * HID;  // rows 64..95

    const int bid = blockIdx.x;
    if (bid < nt) {
        node_tile<256, true, false>(emb1, n_map, nullptr, W1, A, B, a1, b1,
                                    n_nodes, bid * 64, rows, gl);
    } else if (bid < 2 * nt) {
        node_tile<128, false, false>(emb0, n_map, nullptr, W0, A, nullptr, a0,
                                     nullptr, n_nodes, (bid - nt) * 64, rows, gl);
    } else if (bid < 3 * nt) {
        node_tile<64, false, false>(emb2, n_map, nullptr, W2, B, nullptr, b2,
                                    nullptr, n_nodes, (bid - 2 * nt) * 64, rows, gl);
    } else {
        node_tile<64, false, true>(emb2, n_map, offset_node, W2, T, nullptr, t2,
                                   nullptr, batch, (bid - 3 * nt) * 64, rows, gl);
    }
}

// ---------------------------------------------------------------------------
// Per-edge: att = relu(SA[src] + DB[dst] + t2[batch] + be1) @ We2 + be2
// Writes att to its own slab and MIN_WEIGHT to the other slab (the two hop
// index sets partition [0,E), so the two edge launches cover all of d_out).
__global__ __launch_bounds__(256) void edge_kernel(
    const int* __restrict__ hop_idx, int n_e, const int* __restrict__ src,
    const int* __restrict__ dst, const int* __restrict__ e_batch,
    const float* __restrict__ SA, const float* __restrict__ DB,
    const float* __restrict__ t2, const float* __restrict__ be1,
    const float* __restrict__ We2, const float* __restrict__ be2,
    float* __restrict__ out_att, float* __restrict__ out_min) {
    int i = blockIdx.x * blockDim.x + threadIdx.x;
    if (i >= n_e) return;
    int e = hop_idx[i];
    const float* sv = SA + (size_t)src[e] * HID;
    const float* dv = DB + (size_t)dst[e] * HID;
    const float* tv = t2 + (size_t)e_batch[e] * HID;
    float att = be2[0];
#pragma unroll
    for (int k = 0; k < HID; k += 4) {
        float4 s4 = *(const float4*)(sv + k);
        float4 d4 = *(const float4*)(dv + k);
        float4 t4 = *(const float4*)(tv + k);
        float h;
        h = fmaxf(s4.x + d4.x + t4.x + be1[k + 0], 0.f); att = fmaf(h, We2[k + 0], att);
        h = fmaxf(s4.y + d4.y + t4.y + be1[k + 1], 0.f); att = fmaf(h, We2[k + 1], att);
        h = fmaxf(s4.z + d4.z + t4.z + be1[k + 2], 0.f); att = fmaf(h, We2[k + 2], att);
        h = fmaxf(s4.w + d4.w + t4.w + be1[k + 3], 0.f); att = fmaf(h, We2[k + 3], att);
    }
    out_att[e] = att;
    out_min[e] = MIN_WEIGHT;
}

// ---------------------------------------------------------------------------
extern "C" void kernel_launch(void* const* d_in, const int* in_sizes, int n_in,
                              void* d_out, int out_size, void* d_ws, size_t ws_size,
                              hipStream_t stream) {
    const float* emb0 = (const float*)d_in[0];
    const float* emb1 = (const float*)d_in[1];
    const float* emb2 = (const float*)d_in[2];
    const int* n_map = (const int*)d_in[3];
    const int* src = (const int*)d_in[4];
    const int* dst = (const int*)d_in[5];
    const int* e_batch = (const int*)d_in[6];
    const int* offset_node = (const int*)d_in[7];
    const int* one_hop = (const int*)d_in[8];
    const int* two_hop = (const int*)d_in[9];
    const float* W0 = (const float*)d_in[10];
    const float* W1 = (const float*)d_in[11];
    const float* W2 = (const float*)d_in[12];
    const float* We1 = (const float*)d_in[13];
    const float* be1 = (const float*)d_in[14];
    const float* We2 = (const float*)d_in[15];
    const float* be2 = (const float*)d_in[16];

    const int n_nodes = in_sizes[3];
    const int E = in_sizes[4];
    const int batch = in_sizes[7];
    const int H1 = in_sizes[8];  // one-hop edge count
    const int H2 = in_sizes[9];  // two-hop edge count

    float* out = (float*)d_out;

    // workspace layout: a0 | a1 | b1 | b2 | t2
    float* a0 = (float*)d_ws;
    float* a1 = a0 + (size_t)n_nodes * HID;
    float* b1 = a1 + (size_t)n_nodes * HID;
    float* b2 = b1 + (size_t)n_nodes * HID;
    float* t2 = b2 + (size_t)n_nodes * HID;

    const int nt = (n_nodes + 63) / 64;          // tiles per node job
    const int nt_t2 = (batch + 63) / 64;         // tiles for t2 job
    nodek_fused<<<3 * nt + nt_t2, 256, 0, stream>>>(
        emb0, emb1, emb2, n_map, offset_node, W0, W1, W2, We1,
        a0, a1, b1, b2, t2, n_nodes, batch, nt);

    // one-hop edges: att -> slab 1, MIN -> slab 0 (src via W1@A, dst via W2@B)
    edge_kernel<<<(H1 + 255) / 256, 256, 0, stream>>>(
        one_hop, H1, src, dst, e_batch, a1, b2, t2, be1, We2, be2,
        out + (size_t)E, out);
    // two-hop edges: att -> slab 0, MIN -> slab 1 (src via W0@A, dst via W1@B)
    edge_kernel<<<(H2 + 255) / 256, 256, 0, stream>>>(
        two_hop, H2, src, dst, e_batch, a0, b1, t2, be1, We2, be2,
        out, out + (size_t)E);
}

// Round 10
// 227.217 us; speedup vs baseline: 1.1886x; 1.1085x over previous
//
#include <hip/hip_runtime.h>

#define HID 32
#define MIN_WEIGHT -100000.0f

// ---------------------------------------------------------------------------
// async global->LDS, 16B per lane, wave-uniform LDS base (+lane*16 implicit)
__device__ __forceinline__ void gld16(const float* g, float* l) {
    __builtin_amdgcn_global_load_lds(
        (const __attribute__((address_space(1))) unsigned int*)g,
        (__attribute__((address_space(3))) unsigned int*)l, 16, 0, 0);
}

// ---------------------------------------------------------------------------
// Node-stage kernel, zero-VMEM inner loops. Block = 256 thr / 4 waves,
// TILE = 16 nodes.
//   once/block VMEM: stage 16 rows (global_load_lds, linear LDS), load W
//     K-slice into REGISTERS (wave w owns K in [w*KW,(w+1)*KW), lane (h,c)
//     holds wreg[KW] = W[.][c]), copy P0/P1 into LDS (float4, coalesced).
//   layer 1: acc(node r=2p+h, col c) += rows[r][w*KW+j] * wreg[j]
//     - rows read ds_read_b128, 2 distinct addrs/instr (broadcast), banks
//       j0..j0+3 -> 2-way = free;  W = register; NO memory on the chain.
//   reduce : partials part[4][16][36] summed over waves (+relu) -> gl[16][36]
//   proj   : thread=(row,16 col-pairs): g b128 broadcast + P float2 from LDS.
// All cache-missable traffic is once-per-block and overlapped by vmcnt(0).
template <int ROW, bool TWO, bool SEL>
__global__ __launch_bounds__(256) void nodek(
    const float* __restrict__ emb, const int* __restrict__ n_map,
    const int* __restrict__ sel, const float* __restrict__ W,
    const float* __restrict__ P0, const float* __restrict__ P1,
    float* __restrict__ o0, float* __restrict__ o1, int n) {
    constexpr int KW = ROW / 4;   // K-slice per wave
    constexpr int CPR = ROW / 4;  // 16B chunks per row
    constexpr int RPI = 64 / CPR; // rows per staging instruction
    constexpr int IPW = 4 / RPI;  // staging instructions per wave (4 rows/wave)

    __shared__ float rows[16 * ROW];
    __shared__ float part[4 * 16 * 36];
    __shared__ float gl[16 * 36];
    __shared__ float Pl[(TWO ? 2 : 1) * 1024];

    const int tid = threadIdx.x;
    const int w = __builtin_amdgcn_readfirstlane(tid >> 6);
    const int lane = tid & 63;
    const int base = blockIdx.x * 16;

    // ---- once/block: P -> LDS (coalesced float4) --------------------------
    {
        float4 v = *(const float4*)&P0[tid * 4];
        *(float4*)&Pl[tid * 4] = v;
        if (TWO) {
            float4 u = *(const float4*)&P1[tid * 4];
            *(float4*)&Pl[1024 + tid * 4] = u;
        }
    }

    // ---- once/block: stage my wave's 4 rows -------------------------------
    {
        const int sub = lane / CPR;
        const int chunk = lane % CPR;
#pragma unroll
        for (int i = 0; i < IPW; ++i) {
            const int r = 4 * w + i * RPI + sub;
            int node = base + r;
            int cn = node < n ? node : n - 1;  // clamp, lanes stay active
            int local = SEL ? sel[cn] : cn;
            int gn = n_map[local];
            gld16(emb + (size_t)gn * ROW + chunk * 4,
                  &rows[(4 * w + i * RPI) * ROW]);
        }
    }

    // ---- once/block: W K-slice -> registers (statically indexed) ----------
    const int c = lane & 31;
    const int h = lane >> 5;
    float wreg[KW];
#pragma unroll
    for (int jj = 0; jj < KW; ++jj)
        wreg[jj] = W[(size_t)(w * KW + jj) * HID + c];

    asm volatile("s_waitcnt vmcnt(0)" ::: "memory");
    __builtin_amdgcn_sched_barrier(0);

    // ---- layer 1: pure ds_read + FMA --------------------------------------
#pragma unroll 2
    for (int p = 0; p < 8; ++p) {
        const int r = 2 * p + h;
        float acc = 0.f;
#pragma unroll
        for (int j0 = 0; j0 < KW; j0 += 4) {
            float4 r4 = *(const float4*)&rows[r * ROW + w * KW + j0];
            acc = fmaf(r4.x, wreg[j0 + 0], acc);
            acc = fmaf(r4.y, wreg[j0 + 1], acc);
            acc = fmaf(r4.z, wreg[j0 + 2], acc);
            acc = fmaf(r4.w, wreg[j0 + 3], acc);
        }
        part[(w * 16 + r) * 36 + c] = acc;
    }
    __syncthreads();

    // ---- reduce over K-slices + relu --------------------------------------
#pragma unroll
    for (int rep = 0; rep < 2; ++rep) {
        int cell = tid + rep * 256;  // 0..511 = 16 nodes x 32 cols
        int node = cell >> 5, cc = cell & 31;
        float s = part[(0 + node) * 36 + cc] + part[(16 + node) * 36 + cc] +
                  part[(32 + node) * 36 + cc] + part[(48 + node) * 36 + cc];
        gl[node * 36 + cc] = fmaxf(s, 0.f);
    }
    __syncthreads();

    // ---- projections: g + P both from LDS ---------------------------------
    const int row = tid >> 4;  // 0..15
    const int cp = tid & 15;   // col pair
    float pa0 = 0.f, pa1 = 0.f, pb0 = 0.f, pb1 = 0.f;
#pragma unroll
    for (int j0 = 0; j0 < HID; j0 += 4) {
        float4 g4 = *(const float4*)&gl[row * 36 + j0];
#pragma unroll
        for (int jj = 0; jj < 4; ++jj) {
            float gv = ((const float*)&g4)[jj];
            float2 p2 = *(const float2*)&Pl[(j0 + jj) * HID + 2 * cp];
            pa0 = fmaf(gv, p2.x, pa0);
            pa1 = fmaf(gv, p2.y, pa1);
            if (TWO) {
                float2 q2 = *(const float2*)&Pl[1024 + (j0 + jj) * HID + 2 * cp];
                pb0 = fmaf(gv, q2.x, pb0);
                pb1 = fmaf(gv, q2.y, pb1);
            }
        }
    }
    int onode = base + row;
    if (onode < n) {
        float2 v = {pa0, pa1};
        *(float2*)&o0[(size_t)onode * HID + 2 * cp] = v;
        if (TWO) {
            float2 u = {pb0, pb1};
            *(float2*)&o1[(size_t)onode * HID + 2 * cp] = u;
        }
    }
}

// ---------------------------------------------------------------------------
// Per-edge: att = relu(SA[src] + DB[dst] + t2[batch] + be1) @ We2 + be2
// Writes att to its own slab and MIN_WEIGHT to the other slab (the two hop
// index sets partition [0,E), so the two edge launches cover all of d_out).
__global__ __launch_bounds__(256) void edge_kernel(
    const int* __restrict__ hop_idx, int n_e, const int* __restrict__ src,
    const int* __restrict__ dst, const int* __restrict__ e_batch,
    const float* __restrict__ SA, const float* __restrict__ DB,
    const float* __restrict__ t2, const float* __restrict__ be1,
    const float* __restrict__ We2, const float* __restrict__ be2,
    float* __restrict__ out_att, float* __restrict__ out_min) {
    int i = blockIdx.x * blockDim.x + threadIdx.x;
    if (i >= n_e) return;
    int e = hop_idx[i];
    const float* sv = SA + (size_t)src[e] * HID;
    const float* dv = DB + (size_t)dst[e] * HID;
    const float* tv = t2 + (size_t)e_batch[e] * HID;
    float att = be2[0];
#pragma unroll
    for (int k = 0; k < HID; k += 4) {
        float4 s4 = *(const float4*)(sv + k);
        float4 d4 = *(const float4*)(dv + k);
        float4 t4 = *(const float4*)(tv + k);
        float h;
        h = fmaxf(s4.x + d4.x + t4.x + be1[k + 0], 0.f); att = fmaf(h, We2[k + 0], att);
        h = fmaxf(s4.y + d4.y + t4.y + be1[k + 1], 0.f); att = fmaf(h, We2[k + 1], att);
        h = fmaxf(s4.z + d4.z + t4.z + be1[k + 2], 0.f); att = fmaf(h, We2[k + 2], att);
        h = fmaxf(s4.w + d4.w + t4.w + be1[k + 3], 0.f); att = fmaf(h, We2[k + 3], att);
    }
    out_att[e] = att;
    out_min[e] = MIN_WEIGHT;
}

// ---------------------------------------------------------------------------
extern "C" void kernel_launch(void* const* d_in, const int* in_sizes, int n_in,
                              void* d_out, int out_size, void* d_ws, size_t ws_size,
                              hipStream_t stream) {
    const float* emb0 = (const float*)d_in[0];
    const float* emb1 = (const float*)d_in[1];
    const float* emb2 = (const float*)d_in[2];
    const int* n_map = (const int*)d_in[3];
    const int* src = (const int*)d_in[4];
    const int* dst = (const int*)d_in[5];
    const int* e_batch = (const int*)d_in[6];
    const int* offset_node = (const int*)d_in[7];
    const int* one_hop = (const int*)d_in[8];
    const int* two_hop = (const int*)d_in[9];
    const float* W0 = (const float*)d_in[10];
    const float* W1 = (const float*)d_in[11];
    const float* W2 = (const float*)d_in[12];
    const float* We1 = (const float*)d_in[13];
    const float* be1 = (const float*)d_in[14];
    const float* We2 = (const float*)d_in[15];
    const float* be2 = (const float*)d_in[16];

    const int n_nodes = in_sizes[3];
    const int E = in_sizes[4];
    const int batch = in_sizes[7];
    const int H1 = in_sizes[8];  // one-hop edge count
    const int H2 = in_sizes[9];  // two-hop edge count

    float* out = (float*)d_out;

    const float* A = We1;             // rows 0..31   (multiplies s)
    const float* B = We1 + 32 * HID;  // rows 32..63  (multiplies d)
    const float* T = We1 + 64 * HID;  // rows 64..95  (multiplies t)

    // workspace layout: a0 | a1 | b1 | b2 | t2
    float* a0 = (float*)d_ws;
    float* a1 = a0 + (size_t)n_nodes * HID;
    float* b1 = a1 + (size_t)n_nodes * HID;
    float* b2 = b1 + (size_t)n_nodes * HID;
    float* t2 = b2 + (size_t)n_nodes * HID;

    const int nblk = (n_nodes + 15) / 16;
    // a1 = relu(emb1@W1)@A ; b1 = relu(emb1@W1)@B   (biggest job first)
    nodek<256, true, false><<<nblk, 256, 0, stream>>>(
        emb1, n_map, nullptr, W1, A, B, a1, b1, n_nodes);
    // a0 = relu(emb0@W0)@A
    nodek<128, false, false><<<nblk, 256, 0, stream>>>(
        emb0, n_map, nullptr, W0, A, nullptr, a0, nullptr, n_nodes);
    // b2 = relu(emb2@W2)@B
    nodek<64, false, false><<<nblk, 256, 0, stream>>>(
        emb2, n_map, nullptr, W2, B, nullptr, b2, nullptr, n_nodes);
    // t2 = relu(emb2[n_map[offset_node]]@W2)@T
    nodek<64, false, true><<<(batch + 15) / 16, 256, 0, stream>>>(
        emb2, n_map, offset_node, W2, T, nullptr, t2, nullptr, batch);

    // one-hop edges: att -> slab 1, MIN -> slab 0 (src via W1@A, dst via W2@B)
    edge_kernel<<<(H1 + 255) / 256, 256, 0, stream>>>(
        one_hop, H1, src, dst, e_batch, a1, b2, t2, be1, We2, be2,
        out + (size_t)E, out);
    // two-hop edges: att -> slab 0, MIN -> slab 1 (src via W0@A, dst via W1@B)
    edge_kernel<<<(H2 + 255) / 256, 256, 0, stream>>>(
        two_hop, H2, src, dst, e_batch, a0, b1, t2, be1, We2, be2,
        out, out + (size_t)E);
}